// Round 8
// baseline (142.467 us; speedup 1.0000x reference)
//
#include <hip/hip_runtime.h>
#include <math.h>

#define N_PTS 16384
#define NQ (2 * N_PTS)           // combined query space (pred rows + gt rows)
#define TPB 256                  // 4 waves per block
#define QB 256                   // queries per block (4 waves x 64)
#define TB 512                   // targets per block chunk
#define NTC (N_PTS / TB)         // 32 target chunks
#define NQC (NQ / QB)            // 128 query chunks
#define GRID (NQC * NTC)         // 4096 blocks
#define INF 3.0e38f

typedef short bf16x8 __attribute__((ext_vector_type(8)));
typedef float f32x16 __attribute__((ext_vector_type(16)));

__device__ __forceinline__ unsigned short bf16_rne(float x) {
    unsigned u = __float_as_uint(x);
    unsigned r = u + 0x7FFFu + ((u >> 16) & 1u);
    return (unsigned short)(r >> 16);
}
__device__ __forceinline__ float ubf(unsigned short h) {
    return __uint_as_float(((unsigned)h) << 16);
}

// K-slot layout (K=16), D[target,query] = |p-g|^2/2 with C=0:
//  slots 0-2 : T=gh  Q=-ph     slots 3-5 : T=gh  Q=-pl
//  slots 6-8 : T=gl  Q=-ph     slots 9-11: T=gl  Q=-pl
//  slot 12/13: T=wh/wl Q=1,1   (w=|g|^2/2 split)
//  slot 14/15: T=1,1  Q=nh/nl  (n=|p|^2/2 split)

__device__ __forceinline__ void packQ(const float* __restrict__ p, unsigned short* dst) {
    float x = p[0], y = p[1], z = p[2];
    unsigned short xh = bf16_rne(x), yh = bf16_rne(y), zh = bf16_rne(z);
    unsigned short xl = bf16_rne(x - ubf(xh)), yl = bf16_rne(y - ubf(yh)), zl = bf16_rne(z - ubf(zh));
    float nrm = 0.5f * (x * x + y * y + z * z);
    unsigned short nh = bf16_rne(nrm), nl = bf16_rne(nrm - ubf(nh));
    const unsigned short ONE = 0x3F80u, S = 0x8000u;
    union { unsigned short u[16]; bf16x8 v[2]; } pk;
    pk.u[0] = xh ^ S; pk.u[1] = yh ^ S; pk.u[2] = zh ^ S;
    pk.u[3] = xl ^ S; pk.u[4] = yl ^ S; pk.u[5] = zl ^ S;
    pk.u[6] = xh ^ S; pk.u[7] = yh ^ S; pk.u[8] = zh ^ S;
    pk.u[9] = xl ^ S; pk.u[10] = yl ^ S; pk.u[11] = zl ^ S;
    pk.u[12] = ONE; pk.u[13] = ONE; pk.u[14] = nh; pk.u[15] = nl;
    *(bf16x8*)&dst[0] = pk.v[0];
    *(bf16x8*)&dst[8] = pk.v[1];
}

__device__ __forceinline__ void packT(const float* __restrict__ p, unsigned short* dst) {
    float x = p[0], y = p[1], z = p[2];
    unsigned short xh = bf16_rne(x), yh = bf16_rne(y), zh = bf16_rne(z);
    unsigned short xl = bf16_rne(x - ubf(xh)), yl = bf16_rne(y - ubf(yh)), zl = bf16_rne(z - ubf(zh));
    float w = 0.5f * (x * x + y * y + z * z);
    unsigned short wh = bf16_rne(w), wl = bf16_rne(w - ubf(wh));
    const unsigned short ONE = 0x3F80u;
    union { unsigned short u[16]; bf16x8 v[2]; } pk;
    pk.u[0] = xh; pk.u[1] = yh; pk.u[2] = zh;
    pk.u[3] = xh; pk.u[4] = yh; pk.u[5] = zh;
    pk.u[6] = xl; pk.u[7] = yl; pk.u[8] = zl;
    pk.u[9] = xl; pk.u[10] = yl; pk.u[11] = zl;
    pk.u[12] = wh; pk.u[13] = wl; pk.u[14] = ONE; pk.u[15] = ONE;
    *(bf16x8*)&dst[0] = pk.v[0];
    *(bf16x8*)&dst[8] = pk.v[1];
}

__device__ __forceinline__ float mintree16(const f32x16& d, float acc) {
    float t0 = fminf(fminf(d[0], d[1]), d[2]);
    float t1 = fminf(fminf(d[3], d[4]), d[5]);
    float t2 = fminf(fminf(d[6], d[7]), d[8]);
    float t3 = fminf(fminf(d[9], d[10]), d[11]);
    float t4 = fminf(fminf(d[12], d[13]), d[14]);
    float u0 = fminf(fminf(t0, t1), t2);
    float u1 = fminf(fminf(t3, t4), d[15]);
    return fminf(fminf(u0, u1), acc);
}

// Poison-proof min accumulation: key = ~bits(f), f >= 0. Real keys live in
// [~bits(f_max), 0xFFFFFFFF] ~ [0xBD......, 0xFFFFFFFF]; both 0xAAAAAAAA
// poison and zero garbage are below that, so atomicMax always replaces them.
// max over ~bits == min over f (bits monotone for f >= 0).

__global__ __launch_bounds__(TPB) void fused_kernel(const float* __restrict__ pred,
                                                    const float* __restrict__ gt,
                                                    unsigned* __restrict__ minKey,
                                                    float* __restrict__ colorPart,
                                                    unsigned* __restrict__ counter,
                                                    float* __restrict__ out) {
    __shared__ __align__(16) unsigned short ldsQ[QB * 16];  // 8KB
    __shared__ __align__(16) unsigned short ldsT[TB * 16];  // 16KB
    __shared__ float sred[8];
    __shared__ int s_isLast;

    int tid = threadIdx.x;
    int lane = tid & 63, w = tid >> 6;
    int l31 = lane & 31, lh = lane >> 5;
    int qc = blockIdx.x & (NQC - 1);
    int tc = blockIdx.x >> 7;                  // NQC = 128
    int q0 = qc * QB;                          // [0, NQ)
    bool predSide = q0 < N_PTS;
    const float* qArr = predSide ? pred : gt;
    const float* tArr = predSide ? gt : pred;
    int qrow0 = predSide ? q0 : q0 - N_PTS;
    int trow0 = tc * TB;

    // ---- in-block pack: Q one row/thread, T two rows/thread ----
    packQ(qArr + (size_t)(qrow0 + tid) * 6, &ldsQ[tid * 16]);
    packT(tArr + (size_t)(trow0 + tid) * 6, &ldsT[tid * 16]);
    packT(tArr + (size_t)(trow0 + TPB + tid) * 6, &ldsT[(TPB + tid) * 16]);
    __syncthreads();

    // ---- two query B-frags per wave (wave w owns queries q0+w*64 .. +63) ----
    bf16x8 bq0 = *(const bf16x8*)&ldsQ[(w * 64 + l31) * 16 + lh * 8];
    bf16x8 bq1 = *(const bf16x8*)&ldsQ[(w * 64 + 32 + l31) * 16 + lh * 8];

    f32x16 zc;
#pragma unroll
    for (int i = 0; i < 16; i++) zc[i] = 0.0f;

    float qmin0 = INF, qmin1 = INF;
    const bf16x8* A = (const bf16x8*)ldsT;
    bf16x8 a = A[l31 * 2 + lh];
#pragma unroll
    for (int s = 0; s < TB / 32; s++) {
        bf16x8 an = a;
        if (s + 1 < TB / 32) an = A[((s + 1) * 32 + l31) * 2 + lh];   // prefetch
        __builtin_amdgcn_s_setprio(1);
        f32x16 d0 = __builtin_amdgcn_mfma_f32_32x32x16_bf16(a, bq0, zc, 0, 0, 0);
        f32x16 d1 = __builtin_amdgcn_mfma_f32_32x32x16_bf16(a, bq1, zc, 0, 0, 0);
        __builtin_amdgcn_s_setprio(0);
        qmin0 = mintree16(d0, qmin0);
        qmin1 = mintree16(d1, qmin1);
        a = an;
    }

    qmin0 = fminf(qmin0, __shfl_xor(qmin0, 32));
    qmin1 = fminf(qmin1, __shfl_xor(qmin1, 32));
    if (lh == 0) {
        atomicMax(&minKey[q0 + w * 64 + l31], ~__float_as_uint(fmaxf(qmin0, 0.0f)));
        atomicMax(&minKey[q0 + w * 64 + 32 + l31], ~__float_as_uint(fmaxf(qmin1, 0.0f)));
    }

    // ---- color L1 partials: blocks (tc==0, pred side) cover 256 rows each ----
    bool doColor = (tc == 0) && predSide;
    float csum = 0.0f;
    if (doColor) {
        size_t b = (size_t)(q0 + tid) * 6 + 3;
        csum = fabsf(pred[b] - gt[b]) + fabsf(pred[b + 1] - gt[b + 1]) + fabsf(pred[b + 2] - gt[b + 2]);
    }
#pragma unroll
    for (int o = 32; o; o >>= 1) csum += __shfl_down(csum, o);
    if (doColor && lane == 0) sred[w] = csum;
    __syncthreads();
    if (doColor && tid == 0) colorPart[qc] = sred[0] + sred[1] + sred[2] + sred[3];

    // ---- completion protocol (R4-validated): last block finishes ----
    __syncthreads();          // all atomics issued & drained at barrier
    if (tid == 0) {
        __threadfence();
        unsigned old = atomicAdd(counter, 1u);
        s_isLast = (old == 0xAAAAAAAAu + (GRID - 1)) || (old == (unsigned)(GRID - 1));
    }
    __syncthreads();
    if (!s_isLast) return;

    __threadfence();
    float dsum = 0.0f;
    const uint4* MK = (const uint4*)minKey;
#pragma unroll 4
    for (int k = 0; k < NQ / 4 / TPB; k++) {   // 32 iters, 16B/thread coalesced
        uint4 kk = MK[k * TPB + tid];
        float f0 = __uint_as_float(~kk.x), f1 = __uint_as_float(~kk.y);
        float f2 = __uint_as_float(~kk.z), f3 = __uint_as_float(~kk.w);
        dsum += sqrtf(f0 + f0) + sqrtf(f1 + f1) + sqrtf(f2 + f2) + sqrtf(f3 + f3);
    }
    float csumT = (tid < 64) ? colorPart[tid] : 0.0f;
#pragma unroll
    for (int o = 32; o; o >>= 1) { dsum += __shfl_down(dsum, o); csumT += __shfl_down(csumT, o); }
    if (lane == 0) { sred[w] = dsum; sred[4 + w] = csumT; }
    __syncthreads();
    if (tid == 0) {
        float D = sred[0] + sred[1] + sred[2] + sred[3];
        float C = sred[4] + sred[5] + sred[6] + sred[7];
        out[0] = D * (1.0f / N_PTS) + 0.1f * C * (1.0f / (3.0f * N_PTS));
    }
}

extern "C" void kernel_launch(void* const* d_in, const int* in_sizes, int n_in,
                              void* d_out, int out_size, void* d_ws, size_t ws_size,
                              hipStream_t stream) {
    const float* pred = (const float*)d_in[0];
    const float* gt = (const float*)d_in[1];
    char* base = (char*)d_ws;
    unsigned* counter = (unsigned*)base;                 // 4B @ 0
    float* colorPart = (float*)(base + 256);             // 64 floats
    unsigned* minKey = (unsigned*)(base + 4096);         // NQ*4 = 128KB
    float* out = (float*)d_out;

    fused_kernel<<<GRID, TPB, 0, stream>>>(pred, gt, minKey, colorPart, counter, out);
}

// Round 9
// 89.373 us; speedup vs baseline: 1.5941x; 1.5941x over previous
//
#include <hip/hip_runtime.h>
#include <math.h>

#define N_PTS 16384
#define NQ (2 * N_PTS)           // combined query space (pred rows + gt rows)
#define TPB 256                  // 4 waves per block
#define TA 8                     // target frags (32 rows each) held in regs per wave
#define WAVES 4
#define TGRP (TA * 32 * WAVES)   // 1024 targets per block
#define QCHUNK 512               // queries per block
#define ITERS (QCHUNK / 32)      // 16 query frags per block
#define NQC (NQ / QCHUNK)        // 64 query chunks
#define NTG (N_PTS / TGRP)       // 16 target groups
#define INF 3.0e38f

typedef short bf16x8 __attribute__((ext_vector_type(8)));
typedef float f32x16 __attribute__((ext_vector_type(16)));

__device__ __forceinline__ unsigned short bf16_rne(float x) {
    unsigned u = __float_as_uint(x);
    unsigned r = u + 0x7FFFu + ((u >> 16) & 1u);
    return (unsigned short)(r >> 16);
}
__device__ __forceinline__ float ubf(unsigned short h) {
    return __uint_as_float(((unsigned)h) << 16);
}

// K-slot layout (K=16), D[target,query] = |p-g|^2/2 with C=0:
//  slots 0-2 : T=gh  Q=-ph     slots 3-5 : T=gh  Q=-pl
//  slots 6-8 : T=gl  Q=-ph     slots 9-11: T=gl  Q=-pl
//  slot 12/13: T=wh/wl Q=1,1   (w=|g|^2/2 split)
//  slot 14/15: T=1,1  Q=nh/nl  (n=|p|^2/2 split)

__device__ __forceinline__ void packQ(const float* __restrict__ p, unsigned short* dst) {
    float x = p[0], y = p[1], z = p[2];
    unsigned short xh = bf16_rne(x), yh = bf16_rne(y), zh = bf16_rne(z);
    unsigned short xl = bf16_rne(x - ubf(xh)), yl = bf16_rne(y - ubf(yh)), zl = bf16_rne(z - ubf(zh));
    float nrm = 0.5f * (x * x + y * y + z * z);
    unsigned short nh = bf16_rne(nrm), nl = bf16_rne(nrm - ubf(nh));
    const unsigned short ONE = 0x3F80u, S = 0x8000u;
    union { unsigned short u[16]; bf16x8 v[2]; } pk;
    pk.u[0] = xh ^ S; pk.u[1] = yh ^ S; pk.u[2] = zh ^ S;
    pk.u[3] = xl ^ S; pk.u[4] = yl ^ S; pk.u[5] = zl ^ S;
    pk.u[6] = xh ^ S; pk.u[7] = yh ^ S; pk.u[8] = zh ^ S;
    pk.u[9] = xl ^ S; pk.u[10] = yl ^ S; pk.u[11] = zl ^ S;
    pk.u[12] = ONE; pk.u[13] = ONE; pk.u[14] = nh; pk.u[15] = nl;
    *(bf16x8*)&dst[0] = pk.v[0];
    *(bf16x8*)&dst[8] = pk.v[1];
}

__device__ __forceinline__ void packT(const float* __restrict__ p, unsigned short* dst) {
    float x = p[0], y = p[1], z = p[2];
    unsigned short xh = bf16_rne(x), yh = bf16_rne(y), zh = bf16_rne(z);
    unsigned short xl = bf16_rne(x - ubf(xh)), yl = bf16_rne(y - ubf(yh)), zl = bf16_rne(z - ubf(zh));
    float w = 0.5f * (x * x + y * y + z * z);
    unsigned short wh = bf16_rne(w), wl = bf16_rne(w - ubf(wh));
    const unsigned short ONE = 0x3F80u;
    union { unsigned short u[16]; bf16x8 v[2]; } pk;
    pk.u[0] = xh; pk.u[1] = yh; pk.u[2] = zh;
    pk.u[3] = xh; pk.u[4] = yh; pk.u[5] = zh;
    pk.u[6] = xl; pk.u[7] = yl; pk.u[8] = zl;
    pk.u[9] = xl; pk.u[10] = yl; pk.u[11] = zl;
    pk.u[12] = wh; pk.u[13] = wl; pk.u[14] = ONE; pk.u[15] = ONE;
    *(bf16x8*)&dst[0] = pk.v[0];
    *(bf16x8*)&dst[8] = pk.v[1];
}

__device__ __forceinline__ float mintree16(const f32x16& d, float acc) {
    float t0 = fminf(fminf(d[0], d[1]), d[2]);
    float t1 = fminf(fminf(d[3], d[4]), d[5]);
    float t2 = fminf(fminf(d[6], d[7]), d[8]);
    float t3 = fminf(fminf(d[9], d[10]), d[11]);
    float t4 = fminf(fminf(d[12], d[13]), d[14]);
    float u0 = fminf(fminf(t0, t1), t2);
    float u1 = fminf(fminf(t3, t4), d[15]);
    return fminf(fminf(u0, u1), acc);
}

__global__ __launch_bounds__(256) void prep_kernel(const float* __restrict__ pred,
                                                   const float* __restrict__ gt,
                                                   unsigned short* __restrict__ Qpk,
                                                   unsigned short* __restrict__ Tpk,
                                                   float* __restrict__ colorPart) {
    int i = blockIdx.x * 256 + threadIdx.x;   // 0..NQ-1
    const float* p = (i < N_PTS) ? (pred + (size_t)i * 6) : (gt + (size_t)(i - N_PTS) * 6);
    packQ(p, &Qpk[(size_t)i * 16]);
    packT(p, &Tpk[(size_t)i * 16]);

    float csum = 0.0f;
    if (i < N_PTS) {
        size_t b = (size_t)i * 6 + 3;
        csum = fabsf(pred[b] - gt[b]) + fabsf(pred[b + 1] - gt[b + 1]) + fabsf(pred[b + 2] - gt[b + 2]);
    }
#pragma unroll
    for (int o = 32; o; o >>= 1) csum += __shfl_down(csum, o);
    if ((threadIdx.x & 63) == 0) colorPart[i >> 6] = csum;   // [0, NQ/64)
}

// Poison-proof min accumulation: key = ~bits(max(f,0)). Real keys (f < 1e12)
// all exceed 0xAAAAAAAA poison and zero garbage, so atomicMax needs no init.
// max over ~bits == min over f (bits monotone for f >= 0). Validated R8.
//
// No LDS at all: 8 target A-frags live in registers per wave; query B-frags
// stream from global (2MB Qpk/Tpk are L2-resident). No __syncthreads anywhere.
__global__ __launch_bounds__(TPB) void pairs_kernel(const unsigned short* __restrict__ Qpk,
                                                    const unsigned short* __restrict__ Tpk,
                                                    unsigned* __restrict__ minKey) {
    int tid = threadIdx.x;
    int lane = tid & 63, w = tid >> 6;
    int l31 = lane & 31, lh = lane >> 5;
    int qc = blockIdx.x & (NQC - 1);
    int tg = blockIdx.x >> 6;                 // NQC = 64
    int q0 = qc * QCHUNK;                     // [0, NQ)
    int trow0 = ((q0 < N_PTS) ? N_PTS : 0) + tg * TGRP + w * (TA * 32);  // opposing side

    // ---- 8 target A-frags into registers (one-time, coalesced L2 reads) ----
    bf16x8 a[TA];
#pragma unroll
    for (int f = 0; f < TA; ++f)
        a[f] = *(const bf16x8*)&Tpk[(size_t)(trow0 + f * 32 + l31) * 16 + lh * 8];

    f32x16 zc;
#pragma unroll
    for (int i = 0; i < 16; i++) zc[i] = 0.0f;

    const bf16x8* Q = (const bf16x8*)&Qpk[(size_t)q0 * 16];
    bf16x8 bq = Q[l31 * 2 + lh];

    for (int qf = 0; qf < ITERS; ++qf) {
        bf16x8 bqn = bq;
        if (qf + 1 < ITERS) bqn = Q[((qf + 1) * 32 + l31) * 2 + lh];   // prefetch

        float qmin = INF;
        // 2-deep pipeline: MFMA f+1 issues while min-tree of f runs
        f32x16 dA = __builtin_amdgcn_mfma_f32_32x32x16_bf16(a[0], bq, zc, 0, 0, 0);
#pragma unroll
        for (int f = 0; f < TA; ++f) {
            f32x16 dB = dA;
            if (f + 1 < TA)
                dB = __builtin_amdgcn_mfma_f32_32x32x16_bf16(a[f + 1], bq, zc, 0, 0, 0);
            qmin = mintree16(dA, qmin);
            dA = dB;
        }

        qmin = fminf(qmin, __shfl_xor(qmin, 32));   // combine lh halves (rows)
        if (lane < 32)
            atomicMax(&minKey[q0 + qf * 32 + l31], ~__float_as_uint(fmaxf(qmin, 0.0f)));
        bq = bqn;
    }
}

__global__ __launch_bounds__(1024) void finish_kernel(const unsigned* __restrict__ minKey,
                                                      const float* __restrict__ colorPart,
                                                      float* __restrict__ out) {
    __shared__ float sD[16], sC[16];
    int tid = threadIdx.x;
    int lane = tid & 63, w = tid >> 6;

    float dsum = 0.0f;
    const uint4* MK = (const uint4*)minKey;
#pragma unroll
    for (int k = 0; k < NQ / 4 / 1024; k++) {   // 8 iters, 16B/thread coalesced
        uint4 kk = MK[k * 1024 + tid];
        float f0 = __uint_as_float(~kk.x), f1 = __uint_as_float(~kk.y);
        float f2 = __uint_as_float(~kk.z), f3 = __uint_as_float(~kk.w);
        dsum += sqrtf(f0 + f0) + sqrtf(f1 + f1) + sqrtf(f2 + f2) + sqrtf(f3 + f3);
    }
    float csum = (tid < NQ / 64) ? colorPart[tid] : 0.0f;

#pragma unroll
    for (int o = 32; o; o >>= 1) { dsum += __shfl_down(dsum, o); csum += __shfl_down(csum, o); }
    if (lane == 0) { sD[w] = dsum; sC[w] = csum; }
    __syncthreads();
    if (tid == 0) {
        float D = 0.0f, C = 0.0f;
#pragma unroll
        for (int i = 0; i < 16; i++) { D += sD[i]; C += sC[i]; }
        out[0] = D * (1.0f / N_PTS) + 0.1f * C * (1.0f / (3.0f * N_PTS));
    }
}

extern "C" void kernel_launch(void* const* d_in, const int* in_sizes, int n_in,
                              void* d_out, int out_size, void* d_ws, size_t ws_size,
                              hipStream_t stream) {
    const float* pred = (const float*)d_in[0];
    const float* gt = (const float*)d_in[1];
    char* base = (char*)d_ws;
    float* colorPart = (float*)(base + 256);                  // 512 floats
    unsigned* minKey = (unsigned*)(base + 4096);              // NQ*4 = 128KB
    unsigned short* Qpk = (unsigned short*)(base + 256 * 1024);  // 1MB
    unsigned short* Tpk = Qpk + (size_t)NQ * 16;                 // 1MB
    float* out = (float*)d_out;

    prep_kernel<<<NQ / 256, 256, 0, stream>>>(pred, gt, Qpk, Tpk, colorPart);
    pairs_kernel<<<NQC * NTG, TPB, 0, stream>>>(Qpk, Tpk, minKey);
    finish_kernel<<<1, 1024, 0, stream>>>(minKey, colorPart, out);
}

// Round 10
// 78.603 us; speedup vs baseline: 1.8125x; 1.1370x over previous
//
#include <hip/hip_runtime.h>
#include <math.h>

#define N_PTS 16384
#define NQ (2 * N_PTS)           // combined query space (pred rows + gt rows)
#define TPB 512                  // 8 waves per block
#define QCHUNK 512               // queries per block
#define TGRP 1024                // targets per block (128 per wave)
#define NQC (NQ / QCHUNK)        // 64 query chunks
#define NTG (N_PTS / TGRP)       // 16 target groups
#define TA 4                     // target A-frags (32 rows each) in regs per wave
#define ITERS (QCHUNK / 32)      // 16 query frags per block
#define INF 3.0e38f

typedef short bf16x8 __attribute__((ext_vector_type(8)));
typedef float f32x16 __attribute__((ext_vector_type(16)));

__device__ __forceinline__ unsigned short bf16_rne(float x) {
    unsigned u = __float_as_uint(x);
    unsigned r = u + 0x7FFFu + ((u >> 16) & 1u);
    return (unsigned short)(r >> 16);
}
__device__ __forceinline__ float ubf(unsigned short h) {
    return __uint_as_float(((unsigned)h) << 16);
}

// Swizzled ushort index for (row, 16B-half). byte = row*32 + h*16, then
// byte ^= (row&7)<<4: within each 8-row group the 16 lane-slots cover all 32
// banks exactly once -> every wave64 b128 LDS access is bandwidth-bound.
__device__ __forceinline__ int swz(int row, int h) {
    int byte = (row << 5) + (h << 4);
    byte ^= (row & 7) << 4;
    return byte >> 1;
}

// K-slot layout (K=16), D[target,query] = |p-g|^2/2 with C=0:
//  slots 0-2 : T=gh  Q=-ph     slots 3-5 : T=gh  Q=-pl
//  slots 6-8 : T=gl  Q=-ph     slots 9-11: T=gl  Q=-pl
//  slot 12/13: T=wh/wl Q=1,1   (w=|g|^2/2 split)
//  slot 14/15: T=1,1  Q=nh/nl  (n=|p|^2/2 split)

__device__ __forceinline__ void packQ_lds(const float* __restrict__ p,
                                          unsigned short* __restrict__ lds, int row) {
    float2 r01 = *(const float2*)(p + 0);
    float2 r23 = *(const float2*)(p + 2);
    float x = r01.x, y = r01.y, z = r23.x;
    unsigned short xh = bf16_rne(x), yh = bf16_rne(y), zh = bf16_rne(z);
    unsigned short xl = bf16_rne(x - ubf(xh)), yl = bf16_rne(y - ubf(yh)), zl = bf16_rne(z - ubf(zh));
    float nrm = 0.5f * (x * x + y * y + z * z);
    unsigned short nh = bf16_rne(nrm), nl = bf16_rne(nrm - ubf(nh));
    const unsigned short ONE = 0x3F80u, S = 0x8000u;
    union { unsigned short u[16]; bf16x8 v[2]; } pk;
    pk.u[0] = xh ^ S; pk.u[1] = yh ^ S; pk.u[2] = zh ^ S;
    pk.u[3] = xl ^ S; pk.u[4] = yl ^ S; pk.u[5] = zl ^ S;
    pk.u[6] = xh ^ S; pk.u[7] = yh ^ S; pk.u[8] = zh ^ S;
    pk.u[9] = xl ^ S; pk.u[10] = yl ^ S; pk.u[11] = zl ^ S;
    pk.u[12] = ONE; pk.u[13] = ONE; pk.u[14] = nh; pk.u[15] = nl;
    *(bf16x8*)&lds[swz(row, 0)] = pk.v[0];
    *(bf16x8*)&lds[swz(row, 1)] = pk.v[1];
}

__device__ __forceinline__ void packT_lds(const float* __restrict__ p,
                                          unsigned short* __restrict__ lds, int row) {
    float2 r01 = *(const float2*)(p + 0);
    float2 r23 = *(const float2*)(p + 2);
    float x = r01.x, y = r01.y, z = r23.x;
    unsigned short xh = bf16_rne(x), yh = bf16_rne(y), zh = bf16_rne(z);
    unsigned short xl = bf16_rne(x - ubf(xh)), yl = bf16_rne(y - ubf(yh)), zl = bf16_rne(z - ubf(zh));
    float wn = 0.5f * (x * x + y * y + z * z);
    unsigned short wh = bf16_rne(wn), wl = bf16_rne(wn - ubf(wh));
    const unsigned short ONE = 0x3F80u;
    union { unsigned short u[16]; bf16x8 v[2]; } pk;
    pk.u[0] = xh; pk.u[1] = yh; pk.u[2] = zh;
    pk.u[3] = xh; pk.u[4] = yh; pk.u[5] = zh;
    pk.u[6] = xl; pk.u[7] = yl; pk.u[8] = zl;
    pk.u[9] = xl; pk.u[10] = yl; pk.u[11] = zl;
    pk.u[12] = wh; pk.u[13] = wl; pk.u[14] = ONE; pk.u[15] = ONE;
    *(bf16x8*)&lds[swz(row, 0)] = pk.v[0];
    *(bf16x8*)&lds[swz(row, 1)] = pk.v[1];
}

__device__ __forceinline__ float mintree16(const f32x16& d, float acc) {
    float t0 = fminf(fminf(d[0], d[1]), d[2]);
    float t1 = fminf(fminf(d[3], d[4]), d[5]);
    float t2 = fminf(fminf(d[6], d[7]), d[8]);
    float t3 = fminf(fminf(d[9], d[10]), d[11]);
    float t4 = fminf(fminf(d[12], d[13]), d[14]);
    float u0 = fminf(fminf(t0, t1), t2);
    float u1 = fminf(fminf(t3, t4), d[15]);
    return fminf(fminf(u0, u1), acc);
}

// Poison-proof min merge: key = ~bits(max(f,0)); real keys beat 0xAA poison
// and zero garbage, so atomicMax needs no init pass. Validated R8/R9.
__global__ __launch_bounds__(TPB, 4) void fused_kernel(const float* __restrict__ pred,
                                                       const float* __restrict__ gt,
                                                       unsigned* __restrict__ minKey,
                                                       float* __restrict__ colorPart) {
    __shared__ __align__(16) unsigned short ldsQ[QCHUNK * 16];  // 16KB swizzled
    __shared__ __align__(16) unsigned short ldsT[TGRP * 16];    // 32KB swizzled

    int tid = threadIdx.x;
    int lane = tid & 63, w = tid >> 6;
    int l31 = lane & 31, lh = lane >> 5;
    int qc = blockIdx.x & (NQC - 1);
    int tg = blockIdx.x >> 6;                  // NQC = 64
    int q0 = qc * QCHUNK;                      // [0, NQ)
    bool predSide = q0 < N_PTS;
    const float* qArr = predSide ? pred : gt;
    const float* tArr = predSide ? gt : pred;
    int qrow0 = predSide ? q0 : q0 - N_PTS;
    int trow0 = tg * TGRP;                     // opposing side rows

    // ---- in-block pack (swizzled writes; 8-row groups cover all banks) ----
    packT_lds(tArr + (size_t)(trow0 + tid) * 6, ldsT, tid);
    packT_lds(tArr + (size_t)(trow0 + TPB + tid) * 6, ldsT, TPB + tid);
    packQ_lds(qArr + (size_t)(qrow0 + tid) * 6, ldsQ, tid);

    // ---- color L1 (only 32 pred-side tg==0 blocks; block-uniform, no diverge) ----
    if (predSide && tg == 0) {
        size_t b = (size_t)(qrow0 + tid) * 6 + 3;
        float csum = fabsf(pred[b] - gt[b]) + fabsf(pred[b + 1] - gt[b + 1])
                   + fabsf(pred[b + 2] - gt[b + 2]);
#pragma unroll
        for (int o = 32; o; o >>= 1) csum += __shfl_down(csum, o);
        if (lane == 0) colorPart[qc * 8 + w] = csum;   // 32*8 = 256 entries
    }
    __syncthreads();

    // ---- TA target A-frags into regs (one-time, conflict-free swizzled reads) ----
    bf16x8 a[TA];
#pragma unroll
    for (int f = 0; f < TA; ++f)
        a[f] = *(const bf16x8*)&ldsT[swz(w * (TA * 32) + f * 32 + l31, lh)];

    f32x16 zc;
#pragma unroll
    for (int i = 0; i < 16; i++) zc[i] = 0.0f;

    // ---- main loop: stream 16 query B-frags from LDS; 4 MFMAs per read ----
    bf16x8 bq = *(const bf16x8*)&ldsQ[swz(l31, lh)];
    for (int qf = 0; qf < ITERS; ++qf) {
        int nqf = (qf + 1 < ITERS) ? qf + 1 : qf;
        bf16x8 bqn = *(const bf16x8*)&ldsQ[swz(nqf * 32 + l31, lh)];

        float qmin = INF;
        f32x16 dA = __builtin_amdgcn_mfma_f32_32x32x16_bf16(a[0], bq, zc, 0, 0, 0);
#pragma unroll
        for (int f = 0; f < TA; ++f) {
            f32x16 dB = dA;
            if (f + 1 < TA)
                dB = __builtin_amdgcn_mfma_f32_32x32x16_bf16(a[f + 1], bq, zc, 0, 0, 0);
            qmin = mintree16(dA, qmin);
            dA = dB;
        }

        qmin = fminf(qmin, __shfl_xor(qmin, 32));   // merge lh target halves
        if (lane < 32)
            atomicMax(&minKey[q0 + qf * 32 + l31], ~__float_as_uint(fmaxf(qmin, 0.0f)));
        bq = bqn;
    }
}

__global__ __launch_bounds__(1024) void finish_kernel(const unsigned* __restrict__ minKey,
                                                      const float* __restrict__ colorPart,
                                                      float* __restrict__ out) {
    __shared__ float sD[16], sC[16];
    int tid = threadIdx.x;
    int lane = tid & 63, w = tid >> 6;

    float dsum = 0.0f;
    const uint4* MK = (const uint4*)minKey;
#pragma unroll
    for (int k = 0; k < NQ / 4 / 1024; k++) {   // 8 iters, 16B/thread coalesced
        uint4 kk = MK[k * 1024 + tid];
        float f0 = __uint_as_float(~kk.x), f1 = __uint_as_float(~kk.y);
        float f2 = __uint_as_float(~kk.z), f3 = __uint_as_float(~kk.w);
        dsum += sqrtf(f0 + f0) + sqrtf(f1 + f1) + sqrtf(f2 + f2) + sqrtf(f3 + f3);
    }
    float csum = (tid < 256) ? colorPart[tid] : 0.0f;

#pragma unroll
    for (int o = 32; o; o >>= 1) { dsum += __shfl_down(dsum, o); csum += __shfl_down(csum, o); }
    if (lane == 0) { sD[w] = dsum; sC[w] = csum; }
    __syncthreads();
    if (tid == 0) {
        float D = 0.0f, C = 0.0f;
#pragma unroll
        for (int i = 0; i < 16; i++) { D += sD[i]; C += sC[i]; }
        out[0] = D * (1.0f / N_PTS) + 0.1f * C * (1.0f / (3.0f * N_PTS));
    }
}

extern "C" void kernel_launch(void* const* d_in, const int* in_sizes, int n_in,
                              void* d_out, int out_size, void* d_ws, size_t ws_size,
                              hipStream_t stream) {
    const float* pred = (const float*)d_in[0];
    const float* gt = (const float*)d_in[1];
    char* base = (char*)d_ws;
    float* colorPart = (float*)(base + 256);       // 256 floats
    unsigned* minKey = (unsigned*)(base + 4096);   // NQ*4 = 128KB
    float* out = (float*)d_out;

    fused_kernel<<<NQC * NTG, TPB, 0, stream>>>(pred, gt, minKey, colorPart);
    finish_kernel<<<1, 1024, 0, stream>>>(minKey, colorPart, out);
}